// Round 10
// baseline (121.671 us; speedup 1.0000x reference)
//
#include <hip/hip_runtime.h>

#define P 256     // H*W
#define CDIM 256
#define SDIM 32

typedef __attribute__((ext_vector_type(8))) short short8;   // 8 bf16 = 4 VGPR
typedef __attribute__((ext_vector_type(4))) float f32x4;
typedef __attribute__((ext_vector_type(4))) unsigned int uint4v;

__device__ inline unsigned int pack2bf(float lo, float hi) {
    unsigned int ul = __builtin_bit_cast(unsigned int, lo);
    unsigned int uh = __builtin_bit_cast(unsigned int, hi);
    ul += 0x7fffu + ((ul >> 16) & 1u);   // RNE
    uh += 0x7fffu + ((uh >> 16) & 1u);
    return (ul >> 16) | (uh & 0xffff0000u);
}

// Fused prep. Blocks [0,1024): eh (4 a-rows x 256 p). Blocks [1024,1056):
// pack W1e -> bf16 MFMA-A-fragment-linear ([m'=a>>4][kc=k>>3][i16=a&15][8]).
__global__ __launch_bounds__(256) void prep_kernel(const float* __restrict__ hid,
                                                   const float* __restrict__ W1,
                                                   const float* __restrict__ b1,
                                                   float* __restrict__ ehb1,
                                                   uint4v* __restrict__ packA) {
    const int blk = blockIdx.x;
    const int tid = threadIdx.x;
    if (blk >= 1024) {
        const int t  = (blk - 1024) * 256 + tid;   // [0, 8192)
        const int a  = ((t >> 9) << 4) | (t & 15);
        const int kc = (t >> 4) & 31;
        const float* src = W1 + (size_t)a * 512 + 256 + kc * 8;
        const float4 f0 = *(const float4*)src;
        const float4 f1 = *(const float4*)(src + 4);
        uint4v u;
        u.x = pack2bf(f0.x, f0.y);
        u.y = pack2bf(f0.z, f0.w);
        u.z = pack2bf(f1.x, f1.y);
        u.w = pack2bf(f1.z, f1.w);
        packA[t] = u;
        return;
    }
    // eh: ehb1[b,a,p] = sum_c W1h[a,c]*hid[b,c,p] + b1[a]  (fp32, exact)
    const int b  = blk >> 6;
    const int a0 = (blk & 63) << 2;    // 4 a-rows per block (uniform -> s_load W1)
    const int p  = tid;
    float acc[4];
#pragma unroll
    for (int i = 0; i < 4; ++i) acc[i] = 0.f;
    const float* hb = hid + (size_t)b * CDIM * P;
    for (int c = 0; c < CDIM; c += 8) {
        float hv[8];
#pragma unroll
        for (int j = 0; j < 8; ++j) hv[j] = hb[(c + j) * P + p];
#pragma unroll
        for (int i = 0; i < 4; ++i) {
            const float* wr = W1 + (size_t)(a0 + i) * 512 + c;
#pragma unroll
            for (int j = 0; j < 8; ++j) acc[i] = fmaf(wr[j], hv[j], acc[i]);
        }
    }
#pragma unroll
    for (int i = 0; i < 4; ++i)
        ehb1[((size_t)b * CDIM + a0 + i) * P + p] = acc[i] + b1[a0 + i];
}

// Kernel B: bf16-MFMA energy, latency-decoupled structure:
//   phase 0: issue ALL 16 enc float4 loads (oldest in vmcnt queue) + ehb1->acc
//            + W2 preload (hidden under staging)
//   phase 1: 4x {fp32 chunk -> LDS, barrier, transpose+pack -> bf16 [64p][256c],
//            barrier} — all loads already in flight, no per-kt HBM stall
//   phase 2: BARRIER-FREE MFMA sweep (af from L2-resident packA) + pure-VALU
//            tanh/W2 epilogue.
__global__ __launch_bounds__(256, 2) void energy_mfma(const float* __restrict__ enc,
                                                      const unsigned char* __restrict__ packA,
                                                      const float* __restrict__ W2,
                                                      const float* __restrict__ ehb1,
                                                      float* __restrict__ partial) {
    __shared__ __align__(16) unsigned char ldsF[64 * 256];   // fp32 [64c][64p] swz chunk, 16KB (reused 4x)
    __shared__ __align__(16) unsigned char ldsB[64 * 512];   // bf16 [64p][256c] swz, 32KB
    __shared__ float red[4];
    const int bid = blockIdx.x;          // 2048
    const int bs  = bid >> 2;            // b*32+s
    const int pq  = bid & 3;             // p-quarter (64p)
    const int b   = bs >> 5;
    const int tid = threadIdx.x;
    const int l   = tid & 63;
    const int w   = tid >> 6;            // wave 0..3 -> a-slice
    const int g   = l >> 4;
    const int i16 = l & 15;
    const int a_base = w * 64;
    const int cg4 = tid >> 4;            // G: c-row (within 16-row round)
    const int p4  = tid & 15;            // G: float4 column
    const int p_r = tid & 63;            // R: pixel
    const int ch  = tid >> 6;            // R: 16-c group (== wave)
    const float* eb   = enc  + (size_t)bs * (CDIM * P) + pq * 64;
    const float* ehbB = ehb1 + (size_t)b  * (CDIM * P) + pq * 64;

    // ---- phase 0: issue ALL enc loads first (they own the head of the vmcnt queue)
    float4 gv[4][4];
#pragma unroll
    for (int kt = 0; kt < 4; ++kt)
#pragma unroll
        for (int r = 0; r < 4; ++r)
            gv[kt][r] = *(const float4*)(eb + (size_t)(kt * 64 + r * 16 + cg4) * P + p4 * 4);
    __builtin_amdgcn_sched_barrier(0);

    // acc init from ehb1 fragment (C/D layout: row=(lane>>4)*4+reg, col=lane&15)
    // + W2 preload — L2/L3-resident, hidden under the staging phases.
    f32x4 acc[4][4];
    float w2v[4][4];
#pragma unroll
    for (int m = 0; m < 4; ++m) {
#pragma unroll
        for (int r = 0; r < 4; ++r) {
            const int a = a_base + m * 16 + g * 4 + r;
            w2v[m][r] = W2[a];
            const float* ehr = ehbB + (size_t)a * P + i16;
#pragma unroll
            for (int n = 0; n < 4; ++n)
                acc[m][n][r] = ehr[n * 16];
        }
    }
    __builtin_amdgcn_sched_barrier(0);

    // ---- phase 1: 4 transpose-stage chunks, back-to-back
#pragma unroll
    for (int kt = 0; kt < 4; ++kt) {
#pragma unroll
        for (int r = 0; r < 4; ++r) {
            const int c = r * 16 + cg4;
            *(float4*)(ldsF + c * 256 + ((p4 * 16) ^ ((c & 7) << 4))) = gv[kt][r];
        }
        __syncthreads();
        float cv[16];
#pragma unroll
        for (int j = 0; j < 16; ++j) {
            const int c = ch * 16 + j;
            cv[j] = *(const float*)(ldsF + c * 256 +
                     ((((p_r >> 2) * 16) ^ ((c & 7) << 4)) | ((p_r & 3) * 4)));
        }
        unsigned char* dst = ldsB + p_r * 512;
#pragma unroll
        for (int h = 0; h < 2; ++h) {
            uint4v u;
            u.x = pack2bf(cv[h*8+0], cv[h*8+1]);
            u.y = pack2bf(cv[h*8+2], cv[h*8+3]);
            u.z = pack2bf(cv[h*8+4], cv[h*8+5]);
            u.w = pack2bf(cv[h*8+6], cv[h*8+7]);
            *(uint4v*)(dst + ((kt * 128 + ch * 32 + h * 16) ^ ((p_r & 7) << 4))) = u;
        }
        __syncthreads();
    }

    // ---- phase 2: barrier-free MFMA sweep over all 256 c
#pragma unroll
    for (int kt = 0; kt < 4; ++kt) {
        short8 af[2][4];
#pragma unroll
        for (int kh = 0; kh < 2; ++kh)
#pragma unroll
            for (int m = 0; m < 4; ++m) {
                const int chunk = ((a_base >> 4) + m) * 32 + kt * 8 + kh * 4;
                af[kh][m] = __builtin_bit_cast(short8,
                    *(const uint4v*)(packA + (size_t)chunk * 256 + l * 16));
            }
#pragma unroll
        for (int kh = 0; kh < 2; ++kh) {
            short8 bf[4];
#pragma unroll
            for (int n = 0; n < 4; ++n) {
                const int row = n * 16 + i16;
                bf[n] = __builtin_bit_cast(short8,
                    *(const uint4v*)(ldsB + row * 512 +
                        ((kt * 128 + (kh * 4 + g) * 16) ^ ((row & 7) << 4))));
            }
#pragma unroll
            for (int m = 0; m < 4; ++m)
#pragma unroll
                for (int n = 0; n < 4; ++n)
                    acc[m][n] = __builtin_amdgcn_mfma_f32_16x16x32_bf16(af[kh][m], bf[n], acc[m][n], 0, 0, 0);
        }
    }

    // epilogue: pure VALU — tanh + W2 dot, 4 independent m-chains
    float epm[4];
#pragma unroll
    for (int m = 0; m < 4; ++m) {
        float e = 0.f;
#pragma unroll
        for (int r = 0; r < 4; ++r) {
            const float wv = w2v[m][r];
#pragma unroll
            for (int n = 0; n < 4; ++n) {
                const float x  = acc[m][n][r];
                const float ex = __expf(2.f * x);
                const float t  = 1.f - 2.f / (ex + 1.f);
                e = fmaf(wv, t, e);
            }
        }
        epm[m] = e;
    }
    float ep = (epm[0] + epm[1]) + (epm[2] + epm[3]);
#pragma unroll
    for (int off = 32; off > 0; off >>= 1) ep += __shfl_down(ep, off, 64);
    if (l == 0) red[w] = ep;
    __syncthreads();
    if (tid == 0)
        partial[(size_t)bs * 4 + pq] = red[0] + red[1] + red[2] + red[3];
}

// Kernel D: fused softmax + context. Each block computes its batch's 32-wide
// softmax from the 128 block-uniform partials (s_loads), then the weighted sum.
__global__ __launch_bounds__(256) void context_kernel(const float4* __restrict__ enc4,
                                                      const float* __restrict__ partial,
                                                      const float* __restrict__ b2,
                                                      float4* __restrict__ out4) {
    const int bi = blockIdx.x;                       // 1024
    const int b  = bi >> 6;
    const int i4 = ((bi & 63) << 8) + threadIdx.x;   // [0,16384) float4s over C*P

    float e[SDIM];
    const float* pb = partial + (size_t)b * SDIM * 4;
    const float bias = b2[0];
#pragma unroll
    for (int s = 0; s < SDIM; ++s)
        e[s] = (pb[s*4] + pb[s*4+1] + pb[s*4+2] + pb[s*4+3]) * (1.f / 256.f) + bias;
    float m = e[0];
#pragma unroll
    for (int s = 1; s < SDIM; ++s) m = fmaxf(m, e[s]);
    float sum = 0.f;
#pragma unroll
    for (int s = 0; s < SDIM; ++s) { e[s] = __expf(e[s] - m); sum += e[s]; }
    const float inv = 1.f / sum;

    float4 acc = {0.f, 0.f, 0.f, 0.f};
    const float4* eb = enc4 + (size_t)b * SDIM * 16384 + i4;
#pragma unroll 4
    for (int s = 0; s < SDIM; ++s) {
        const float wv = e[s] * inv;
        const float4 v = eb[(size_t)s * 16384];
        acc.x = fmaf(wv, v.x, acc.x);
        acc.y = fmaf(wv, v.y, acc.y);
        acc.z = fmaf(wv, v.z, acc.z);
        acc.w = fmaf(wv, v.w, acc.w);
    }
    out4[(size_t)b * 16384 + i4] = acc;
}

extern "C" void kernel_launch(void* const* d_in, const int* in_sizes, int n_in,
                              void* d_out, int out_size, void* d_ws, size_t ws_size,
                              hipStream_t stream) {
    const float* hid = (const float*)d_in[0];
    const float* enc = (const float*)d_in[1];
    const float* W1  = (const float*)d_in[2];
    const float* b1  = (const float*)d_in[3];
    const float* W2  = (const float*)d_in[4];
    const float* b2  = (const float*)d_in[5];
    float* out = (float*)d_out;

    float* ehb1    = out;                       // d_out reused as 4MB scratch
    float* partial = (float*)d_ws;              // 2048 floats
    unsigned char* packA = (unsigned char*)(partial + 2048);  // 128KB bf16 W1e

    prep_kernel<<<1056, 256, 0, stream>>>(hid, W1, b1, ehb1, (uint4v*)packA);
    energy_mfma<<<2048, 256, 0, stream>>>(enc, packA, W2, ehb1, partial);
    context_kernel<<<1024, 256, 0, stream>>>((const float4*)enc, partial, b2, (float4*)out);
}

// Round 11
// 92.160 us; speedup vs baseline: 1.3202x; 1.3202x over previous
//
#include <hip/hip_runtime.h>

#define P 256     // H*W
#define CDIM 256
#define SDIM 32

typedef __attribute__((ext_vector_type(8))) short short8;   // 8 bf16 = 4 VGPR
typedef __attribute__((ext_vector_type(4))) float f32x4;
typedef __attribute__((ext_vector_type(4))) unsigned int uint4v;

__device__ inline unsigned int pack2bf(float lo, float hi) {
    unsigned int ul = __builtin_bit_cast(unsigned int, lo);
    unsigned int uh = __builtin_bit_cast(unsigned int, hi);
    ul += 0x7fffu + ((ul >> 16) & 1u);   // RNE
    uh += 0x7fffu + ((uh >> 16) & 1u);
    return (ul >> 16) | (uh & 0xffff0000u);
}

// Fused prep. Blocks [0,1024): eh (4 a-rows x 256 p). Blocks [1024,1056):
// pack W1e -> bf16 MFMA-A-fragment-linear ([m'=a>>4][kc=k>>3][i16=a&15][8]).
__global__ __launch_bounds__(256) void prep_kernel(const float* __restrict__ hid,
                                                   const float* __restrict__ W1,
                                                   const float* __restrict__ b1,
                                                   float* __restrict__ ehb1,
                                                   uint4v* __restrict__ packA) {
    const int blk = blockIdx.x;
    const int tid = threadIdx.x;
    if (blk >= 1024) {
        const int t  = (blk - 1024) * 256 + tid;   // [0, 8192)
        const int a  = ((t >> 9) << 4) | (t & 15);
        const int kc = (t >> 4) & 31;
        const float* src = W1 + (size_t)a * 512 + 256 + kc * 8;
        const float4 f0 = *(const float4*)src;
        const float4 f1 = *(const float4*)(src + 4);
        uint4v u;
        u.x = pack2bf(f0.x, f0.y);
        u.y = pack2bf(f0.z, f0.w);
        u.z = pack2bf(f1.x, f1.y);
        u.w = pack2bf(f1.z, f1.w);
        packA[t] = u;
        return;
    }
    // eh: ehb1[b,a,p] = sum_c W1h[a,c]*hid[b,c,p] + b1[a]  (fp32, exact)
    const int b  = blk >> 6;
    const int a0 = (blk & 63) << 2;    // 4 a-rows per block (uniform -> s_load W1)
    const int p  = tid;
    float acc[4];
#pragma unroll
    for (int i = 0; i < 4; ++i) acc[i] = 0.f;
    const float* hb = hid + (size_t)b * CDIM * P;
    for (int c = 0; c < CDIM; c += 8) {
        float hv[8];
#pragma unroll
        for (int j = 0; j < 8; ++j) hv[j] = hb[(c + j) * P + p];
#pragma unroll
        for (int i = 0; i < 4; ++i) {
            const float* wr = W1 + (size_t)(a0 + i) * 512 + c;
#pragma unroll
            for (int j = 0; j < 8; ++j) acc[i] = fmaf(wr[j], hv[j], acc[i]);
        }
    }
#pragma unroll
    for (int i = 0; i < 4; ++i)
        ehb1[((size_t)b * CDIM + a0 + i) * P + p] = acc[i] + b1[a0 + i];
}

// Kernel B: bf16-MFMA energy with DMA-staged pipeline (T3/T4):
//   enc -> LDS via global_load_lds (per-lane global addr, linear LDS dest,
//   ZERO VGPR/VALU staging), ring of 3 fp32 buffers = prefetch depth 2 tiles.
//   af (packA, L2) software double-buffered one kt ahead, so every vmcnt wait
//   leaves the newest DMA+af group (12 ops) in flight — never drains to 0
//   in the loop. Raw s_barrier + explicit lgkmcnt(0). ldsB single 8KB tile
//   (proven swizzle, conflict-free).
__global__ __launch_bounds__(256, 2) void energy_mfma(const float* __restrict__ enc,
                                                      const unsigned char* __restrict__ packA,
                                                      const float* __restrict__ W2,
                                                      const float* __restrict__ ehb1,
                                                      float* __restrict__ partial) {
    __shared__ __align__(16) unsigned char bufF[3][64 * 256];  // fp32 [64c][64p] linear, 16KB each
    __shared__ __align__(16) unsigned char ldsB[64 * 128];     // bf16 [64p][64c] swz, 8KB
    __shared__ float red[4];
    const int bid = blockIdx.x;          // 2048
    const int bs  = bid >> 2;            // b*32+s
    const int pq  = bid & 3;             // p-quarter (64p)
    const int b   = bs >> 5;
    const int tid = threadIdx.x;
    const int l   = tid & 63;
    const int w   = tid >> 6;            // wave 0..3 -> a-slice
    const int g   = l >> 4;
    const int i16 = l & 15;
    const int a_base = w * 64;
    const int p_r = tid & 63;            // transpose: pixel
    const int ch  = tid >> 6;            // transpose: 16-c group (== wave)
    const float* eb   = enc  + (size_t)bs * (CDIM * P) + pq * 64;
    const float* ehbB = ehb1 + (size_t)b  * (CDIM * P) + pq * 64;

    // DMA one 64c x 64p fp32 tile: wave w covers c-rows [w*16, w*16+16).
    // Per inst: lane l -> global row c+(l>>4), 16B at p-offset (l&15)*4 floats;
    // LDS dest linear (uniform base + lane*16).
#define DMA_TILE(KT, BUF)                                                          \
    {                                                                              \
        const float* gsrc = eb + (size_t)((KT) * 64 + w * 16) * P;                 \
        unsigned char* ldst = (BUF) + (w * 16) * 256;                              \
        _Pragma("unroll")                                                          \
        for (int i_ = 0; i_ < 4; ++i_) {                                           \
            __builtin_amdgcn_global_load_lds(                                      \
                (const unsigned int*)(gsrc + (size_t)(i_ * 4 + (l >> 4)) * P +     \
                                      (l & 15) * 4),                               \
                (unsigned int*)(ldst + i_ * 1024), 16, 0, 0);                      \
        }                                                                          \
    }

    // Transpose+pack one tile: fp32 [64c][64p] -> bf16 [64p][64c] swizzled.
    // Reads: wave-uniform row + lane-consecutive p -> conflict-free.
#define TRANSPOSE(BUF)                                                             \
    {                                                                              \
        float cv[16];                                                              \
        _Pragma("unroll")                                                          \
        for (int j_ = 0; j_ < 16; ++j_)                                            \
            cv[j_] = *(const float*)((BUF) + (ch * 16 + j_) * 256 + p_r * 4);      \
        unsigned char* dst = ldsB + p_r * 128;                                     \
        _Pragma("unroll")                                                          \
        for (int h_ = 0; h_ < 2; ++h_) {                                           \
            uint4v u;                                                              \
            u.x = pack2bf(cv[h_*8+0], cv[h_*8+1]);                                 \
            u.y = pack2bf(cv[h_*8+2], cv[h_*8+3]);                                 \
            u.z = pack2bf(cv[h_*8+4], cv[h_*8+5]);                                 \
            u.w = pack2bf(cv[h_*8+6], cv[h_*8+7]);                                 \
            *(uint4v*)(dst + ((ch * 32 + h_ * 16) ^ ((p_r & 7) << 4))) = u;        \
        }                                                                          \
    }

    // ---- prologue ----
    // acc init from ehb1 fragment (C/D layout) + W2 preload (80 VMEM, drained
    // by the vmcnt(12) below — L2/L3, cheap).
    f32x4 acc[4][4];
    float w2v[4][4];
#pragma unroll
    for (int m = 0; m < 4; ++m) {
#pragma unroll
        for (int r = 0; r < 4; ++r) {
            const int a = a_base + m * 16 + g * 4 + r;
            w2v[m][r] = W2[a];
            const float* ehr = ehbB + (size_t)a * P + i16;
#pragma unroll
            for (int n = 0; n < 4; ++n)
                acc[m][n][r] = ehr[n * 16];
        }
    }
    __builtin_amdgcn_sched_barrier(0);
    DMA_TILE(0, bufF[0]);                 // 4 VMEM
    DMA_TILE(1, bufF[1]);                 // 4 VMEM
    __builtin_amdgcn_sched_barrier(0);
    // af for kt=0 (8 VMEM, L2)
    short8 af[2][2][4];
#pragma unroll
    for (int kh = 0; kh < 2; ++kh)
#pragma unroll
        for (int m = 0; m < 4; ++m) {
            const int chunk = ((a_base >> 4) + m) * 32 + 0 * 8 + kh * 4;
            af[0][kh][m] = __builtin_bit_cast(short8,
                *(const uint4v*)(packA + (size_t)chunk * 256 + l * 16));
        }
    __builtin_amdgcn_sched_barrier(0);
    asm volatile("s_waitcnt vmcnt(12)" ::: "memory");   // acc+DMA0 done; DMA1+af0 fly
    __builtin_amdgcn_sched_barrier(0);
    __builtin_amdgcn_s_barrier();                       // all waves: bufF[0] ready
    TRANSPOSE(bufF[0]);
    asm volatile("s_waitcnt lgkmcnt(0)" ::: "memory");
    __builtin_amdgcn_sched_barrier(0);
    __builtin_amdgcn_s_barrier();                       // ldsB ready

#pragma unroll
    for (int kt = 0; kt < 4; ++kt) {
        // issue next DMA (depth 2) and next af — BEFORE the MFMA cluster
        if (kt < 2) DMA_TILE(kt + 2, bufF[(kt + 2) % 3]);
        __builtin_amdgcn_sched_barrier(0);
        if (kt < 3) {
#pragma unroll
            for (int kh = 0; kh < 2; ++kh)
#pragma unroll
                for (int m = 0; m < 4; ++m) {
                    const int chunk = ((a_base >> 4) + m) * 32 + (kt + 1) * 8 + kh * 4;
                    af[(kt + 1) & 1][kh][m] = __builtin_bit_cast(short8,
                        *(const uint4v*)(packA + (size_t)chunk * 256 + l * 16));
                }
        }
        __builtin_amdgcn_sched_barrier(0);
        // MFMA on ldsB with af[kt&1] (loaded last iter -> its wait leaves the
        // just-issued DMA+af group in flight)
#pragma unroll
        for (int kh = 0; kh < 2; ++kh) {
            short8 bf[4];
#pragma unroll
            for (int n = 0; n < 4; ++n) {
                const int row = n * 16 + i16;
                bf[n] = __builtin_bit_cast(short8,
                    *(const uint4v*)(ldsB + row * 128 +
                                     (((kh * 4 + g) * 16) ^ ((row & 7) << 4))));
            }
#pragma unroll
            for (int m = 0; m < 4; ++m)
#pragma unroll
                for (int n = 0; n < 4; ++n)
                    acc[m][n] = __builtin_amdgcn_mfma_f32_16x16x32_bf16(af[kt & 1][kh][m], bf[n], acc[m][n], 0, 0, 0);
        }
        // tail: wait DMA(kt+1) (leave DMA(kt+2)+af(kt+1) = 12 in flight), barrier,
        // transpose next tile into ldsB, publish, barrier.
        if (kt == 0 || kt == 1) {
            asm volatile("s_waitcnt vmcnt(12)" ::: "memory");
        } else if (kt == 2) {
            asm volatile("s_waitcnt vmcnt(8)" ::: "memory");
        }
        if (kt < 3) {
            __builtin_amdgcn_sched_barrier(0);
            __builtin_amdgcn_s_barrier();               // MFMA(kt) done everywhere; bufF[kt+1] ready
            TRANSPOSE(bufF[(kt + 1) % 3]);
            asm volatile("s_waitcnt lgkmcnt(0)" ::: "memory");
            __builtin_amdgcn_sched_barrier(0);
            __builtin_amdgcn_s_barrier();               // ldsB ready
        }
    }
#undef DMA_TILE
#undef TRANSPOSE

    // epilogue: pure VALU — tanh + W2 dot, 4 independent m-chains
    float epm[4];
#pragma unroll
    for (int m = 0; m < 4; ++m) {
        float e = 0.f;
#pragma unroll
        for (int r = 0; r < 4; ++r) {
            const float wv = w2v[m][r];
#pragma unroll
            for (int n = 0; n < 4; ++n) {
                const float x  = acc[m][n][r];
                const float ex = __expf(2.f * x);
                const float t  = 1.f - 2.f / (ex + 1.f);
                e = fmaf(wv, t, e);
            }
        }
        epm[m] = e;
    }
    float ep = (epm[0] + epm[1]) + (epm[2] + epm[3]);
#pragma unroll
    for (int off = 32; off > 0; off >>= 1) ep += __shfl_down(ep, off, 64);
    if (l == 0) red[w] = ep;
    __syncthreads();
    if (tid == 0)
        partial[(size_t)bs * 4 + pq] = red[0] + red[1] + red[2] + red[3];
}

// Kernel D: fused softmax + context. Each block computes its batch's 32-wide
// softmax from the 128 block-uniform partials (s_loads), then the weighted sum.
__global__ __launch_bounds__(256) void context_kernel(const float4* __restrict__ enc4,
                                                      const float* __restrict__ partial,
                                                      const float* __restrict__ b2,
                                                      float4* __restrict__ out4) {
    const int bi = blockIdx.x;                       // 1024
    const int b  = bi >> 6;
    const int i4 = ((bi & 63) << 8) + threadIdx.x;   // [0,16384) float4s over C*P

    float e[SDIM];
    const float* pb = partial + (size_t)b * SDIM * 4;
    const float bias = b2[0];
#pragma unroll
    for (int s = 0; s < SDIM; ++s)
        e[s] = (pb[s*4] + pb[s*4+1] + pb[s*4+2] + pb[s*4+3]) * (1.f / 256.f) + bias;
    float m = e[0];
#pragma unroll
    for (int s = 1; s < SDIM; ++s) m = fmaxf(m, e[s]);
    float sum = 0.f;
#pragma unroll
    for (int s = 0; s < SDIM; ++s) { e[s] = __expf(e[s] - m); sum += e[s]; }
    const float inv = 1.f / sum;

    float4 acc = {0.f, 0.f, 0.f, 0.f};
    const float4* eb = enc4 + (size_t)b * SDIM * 16384 + i4;
#pragma unroll 4
    for (int s = 0; s < SDIM; ++s) {
        const float wv = e[s] * inv;
        const float4 v = eb[(size_t)s * 16384];
        acc.x = fmaf(wv, v.x, acc.x);
        acc.y = fmaf(wv, v.y, acc.y);
        acc.z = fmaf(wv, v.z, acc.z);
        acc.w = fmaf(wv, v.w, acc.w);
    }
    out4[(size_t)b * 16384 + i4] = acc;
}

extern "C" void kernel_launch(void* const* d_in, const int* in_sizes, int n_in,
                              void* d_out, int out_size, void* d_ws, size_t ws_size,
                              hipStream_t stream) {
    const float* hid = (const float*)d_in[0];
    const float* enc = (const float*)d_in[1];
    const float* W1  = (const float*)d_in[2];
    const float* b1  = (const float*)d_in[3];
    const float* W2  = (const float*)d_in[4];
    const float* b2  = (const float*)d_in[5];
    float* out = (float*)d_out;

    float* ehb1    = out;                       // d_out reused as 4MB scratch
    float* partial = (float*)d_ws;              // 2048 floats
    unsigned char* packA = (unsigned char*)(partial + 2048);  // 128KB bf16 W1e

    prep_kernel<<<1056, 256, 0, stream>>>(hid, W1, b1, ehb1, (uint4v*)packA);
    energy_mfma<<<2048, 256, 0, stream>>>(enc, packA, W2, ehb1, partial);
    context_kernel<<<1024, 256, 0, stream>>>((const float4*)enc, partial, b2, (float4*)out);
}

// Round 12
// 91.649 us; speedup vs baseline: 1.3276x; 1.0056x over previous
//
#include <hip/hip_runtime.h>

#define P 256     // H*W
#define CDIM 256
#define SDIM 32

typedef __attribute__((ext_vector_type(8))) short short8;   // 8 bf16 = 4 VGPR
typedef __attribute__((ext_vector_type(4))) float f32x4;
typedef __attribute__((ext_vector_type(4))) unsigned int uint4v;

__device__ inline unsigned int pack2bf(float lo, float hi) {
    unsigned int ul = __builtin_bit_cast(unsigned int, lo);
    unsigned int uh = __builtin_bit_cast(unsigned int, hi);
    ul += 0x7fffu + ((ul >> 16) & 1u);   // RNE
    uh += 0x7fffu + ((uh >> 16) & 1u);
    return (ul >> 16) | (uh & 0xffff0000u);
}

// Fused prep. Blocks [0,1024): eh (4 a-rows x 256 p). Blocks [1024,1056):
// pack W1e -> bf16 MFMA-A-fragment-linear ([m'=a>>4][kc=k>>3][i16=a&15][8]).
__global__ __launch_bounds__(256) void prep_kernel(const float* __restrict__ hid,
                                                   const float* __restrict__ W1,
                                                   const float* __restrict__ b1,
                                                   float* __restrict__ ehb1,
                                                   uint4v* __restrict__ packA) {
    const int blk = blockIdx.x;
    const int tid = threadIdx.x;
    if (blk >= 1024) {
        const int t  = (blk - 1024) * 256 + tid;   // [0, 8192)
        const int a  = ((t >> 9) << 4) | (t & 15);
        const int kc = (t >> 4) & 31;
        const float* src = W1 + (size_t)a * 512 + 256 + kc * 8;
        const float4 f0 = *(const float4*)src;
        const float4 f1 = *(const float4*)(src + 4);
        uint4v u;
        u.x = pack2bf(f0.x, f0.y);
        u.y = pack2bf(f0.z, f0.w);
        u.z = pack2bf(f1.x, f1.y);
        u.w = pack2bf(f1.z, f1.w);
        packA[t] = u;
        return;
    }
    // eh: ehb1[b,a,p] = sum_c W1h[a,c]*hid[b,c,p] + b1[a]  (fp32, exact)
    const int b  = blk >> 6;
    const int a0 = (blk & 63) << 2;    // 4 a-rows per block (uniform -> s_load W1)
    const int p  = tid;
    float acc[4];
#pragma unroll
    for (int i = 0; i < 4; ++i) acc[i] = 0.f;
    const float* hb = hid + (size_t)b * CDIM * P;
    for (int c = 0; c < CDIM; c += 8) {
        float hv[8];
#pragma unroll
        for (int j = 0; j < 8; ++j) hv[j] = hb[(c + j) * P + p];
#pragma unroll
        for (int i = 0; i < 4; ++i) {
            const float* wr = W1 + (size_t)(a0 + i) * 512 + c;
#pragma unroll
            for (int j = 0; j < 8; ++j) acc[i] = fmaf(wr[j], hv[j], acc[i]);
        }
    }
#pragma unroll
    for (int i = 0; i < 4; ++i)
        ehb1[((size_t)b * CDIM + a0 + i) * P + p] = acc[i] + b1[a0 + i];
}

// Kernel B: bf16-MFMA energy — SMALL-FOOTPRINT version for occupancy (G1):
//   24KB LDS (one fp32 buf + one bf16 tile) + ~110 live VGPR -> 4 blocks/CU,
//   16 waves/CU. Per kt: transpose -> sync -> DMA(kt+1) issue -> MFMA (hides
//   DMA) -> sync. Inter-block TLP covers the remaining latency; no register
//   prefetch state, no LDS ring (rounds 10/11 showed both backfire).
__global__ __launch_bounds__(256, 4) void energy_mfma(const float* __restrict__ enc,
                                                      const unsigned char* __restrict__ packA,
                                                      const float* __restrict__ W2,
                                                      const float* __restrict__ ehb1,
                                                      float* __restrict__ partial) {
    __shared__ __align__(16) unsigned char bufF[64 * 256];   // fp32 [64c][64p] linear, 16KB
    __shared__ __align__(16) unsigned char ldsB[64 * 128];   // bf16 [64p][64c] swz, 8KB
    __shared__ float red[4];
    const int bid = blockIdx.x;          // 2048
    const int bs  = bid >> 2;            // b*32+s
    const int pq  = bid & 3;             // p-quarter (64p)
    const int b   = bs >> 5;
    const int tid = threadIdx.x;
    const int l   = tid & 63;
    const int w   = tid >> 6;            // wave 0..3 -> a-slice
    const int g   = l >> 4;
    const int i16 = l & 15;
    const int a_base = w * 64;
    const int p_r = tid & 63;            // transpose: pixel
    const int ch  = tid >> 6;            // transpose: 16-c group (== wave)
    const float* eb   = enc  + (size_t)bs * (CDIM * P) + pq * 64;
    const float* ehbB = ehb1 + (size_t)b  * (CDIM * P) + pq * 64;

    // DMA one 64c x 64p fp32 tile (per-lane global addr, linear LDS dest):
    // wave w covers c-rows [w*16, w*16+16); 4 insts x (64 lanes x 16B = 4 rows).
#define DMA_TILE(KT)                                                               \
    {                                                                              \
        const float* gsrc = eb + (size_t)((KT) * 64 + w * 16) * P;                 \
        unsigned char* ldst = bufF + (w * 16) * 256;                               \
        _Pragma("unroll")                                                          \
        for (int i_ = 0; i_ < 4; ++i_) {                                           \
            __builtin_amdgcn_global_load_lds(                                      \
                (const unsigned int*)(gsrc + (size_t)(i_ * 4 + (l >> 4)) * P +     \
                                      (l & 15) * 4),                               \
                (unsigned int*)(ldst + i_ * 1024), 16, 0, 0);                      \
        }                                                                          \
    }

    // Transpose+pack: fp32 [64c][64p] linear -> bf16 [64p][64c] swizzled.
    // Reads wave-uniform row + lane-consecutive p -> 2-way aliasing (free).
#define TRANSPOSE()                                                                \
    {                                                                              \
        float cv[16];                                                              \
        _Pragma("unroll")                                                          \
        for (int j_ = 0; j_ < 16; ++j_)                                            \
            cv[j_] = *(const float*)(bufF + (ch * 16 + j_) * 256 + p_r * 4);       \
        unsigned char* dst = ldsB + p_r * 128;                                     \
        _Pragma("unroll")                                                          \
        for (int h_ = 0; h_ < 2; ++h_) {                                           \
            uint4v u;                                                              \
            u.x = pack2bf(cv[h_*8+0], cv[h_*8+1]);                                 \
            u.y = pack2bf(cv[h_*8+2], cv[h_*8+3]);                                 \
            u.z = pack2bf(cv[h_*8+4], cv[h_*8+5]);                                 \
            u.w = pack2bf(cv[h_*8+6], cv[h_*8+7]);                                 \
            *(uint4v*)(dst + ((ch * 32 + h_ * 16) ^ ((p_r & 7) << 4))) = u;        \
        }                                                                          \
    }

    // ---- prologue: DMA tile 0; ehb1->acc init rides under it ----
    DMA_TILE(0);
    f32x4 acc[4][4];
#pragma unroll
    for (int m = 0; m < 4; ++m) {
#pragma unroll
        for (int r = 0; r < 4; ++r) {
            const int a = a_base + m * 16 + g * 4 + r;
            const float* ehr = ehbB + (size_t)a * P + i16;
#pragma unroll
            for (int n = 0; n < 4; ++n)
                acc[m][n][r] = ehr[n * 16];   // C/D layout: row=(lane>>4)*4+reg
        }
    }
    __syncthreads();   // drains vmcnt(0): DMA0 + acc loads done; bufF ready

#pragma unroll
    for (int kt = 0; kt < 4; ++kt) {
        TRANSPOSE();
        __syncthreads();                 // ldsB ready; bufF consumed
        if (kt < 3) DMA_TILE(kt + 1);    // issue early; hides under MFMA below
#pragma unroll
        for (int kh = 0; kh < 2; ++kh) {
            short8 af[4], bf[4];
#pragma unroll
            for (int m = 0; m < 4; ++m) {
                const int chunk = ((a_base >> 4) + m) * 32 + kt * 8 + kh * 4;
                af[m] = __builtin_bit_cast(short8,
                    *(const uint4v*)(packA + (size_t)chunk * 256 + l * 16));
            }
#pragma unroll
            for (int n = 0; n < 4; ++n) {
                const int row = n * 16 + i16;
                bf[n] = __builtin_bit_cast(short8,
                    *(const uint4v*)(ldsB + row * 128 +
                                     (((kh * 4 + g) * 16) ^ ((row & 7) << 4))));
            }
#pragma unroll
            for (int m = 0; m < 4; ++m)
#pragma unroll
                for (int n = 0; n < 4; ++n)
                    acc[m][n] = __builtin_amdgcn_mfma_f32_16x16x32_bf16(af[m], bf[n], acc[m][n], 0, 0, 0);
        }
        __syncthreads();   // drains vmcnt(0): DMA(kt+1) done; ldsB consumed
    }
#undef DMA_TILE
#undef TRANSPOSE

    // epilogue: W2 reload (L2) + pure-VALU tanh/dot, 4 independent m-chains
    float epm[4];
#pragma unroll
    for (int m = 0; m < 4; ++m) {
        float e = 0.f;
#pragma unroll
        for (int r = 0; r < 4; ++r) {
            const float wv = W2[a_base + m * 16 + g * 4 + r];
#pragma unroll
            for (int n = 0; n < 4; ++n) {
                const float x  = acc[m][n][r];
                const float ex = __expf(2.f * x);
                const float t  = 1.f - 2.f / (ex + 1.f);
                e = fmaf(wv, t, e);
            }
        }
        epm[m] = e;
    }
    float ep = (epm[0] + epm[1]) + (epm[2] + epm[3]);
#pragma unroll
    for (int off = 32; off > 0; off >>= 1) ep += __shfl_down(ep, off, 64);
    if (l == 0) red[w] = ep;
    __syncthreads();
    if (tid == 0)
        partial[(size_t)bs * 4 + pq] = red[0] + red[1] + red[2] + red[3];
}

// Kernel D: fused softmax + context. Each block computes its batch's 32-wide
// softmax from the 128 block-uniform partials (s_loads), then the weighted sum.
__global__ __launch_bounds__(256) void context_kernel(const float4* __restrict__ enc4,
                                                      const float* __restrict__ partial,
                                                      const float* __restrict__ b2,
                                                      float4* __restrict__ out4) {
    const int bi = blockIdx.x;                       // 1024
    const int b  = bi >> 6;
    const int i4 = ((bi & 63) << 8) + threadIdx.x;   // [0,16384) float4s over C*P

    float e[SDIM];
    const float* pb = partial + (size_t)b * SDIM * 4;
    const float bias = b2[0];
#pragma unroll
    for (int s = 0; s < SDIM; ++s)
        e[s] = (pb[s*4] + pb[s*4+1] + pb[s*4+2] + pb[s*4+3]) * (1.f / 256.f) + bias;
    float m = e[0];
#pragma unroll
    for (int s = 1; s < SDIM; ++s) m = fmaxf(m, e[s]);
    float sum = 0.f;
#pragma unroll
    for (int s = 0; s < SDIM; ++s) { e[s] = __expf(e[s] - m); sum += e[s]; }
    const float inv = 1.f / sum;

    float4 acc = {0.f, 0.f, 0.f, 0.f};
    const float4* eb = enc4 + (size_t)b * SDIM * 16384 + i4;
#pragma unroll 4
    for (int s = 0; s < SDIM; ++s) {
        const float wv = e[s] * inv;
        const float4 v = eb[(size_t)s * 16384];
        acc.x = fmaf(wv, v.x, acc.x);
        acc.y = fmaf(wv, v.y, acc.y);
        acc.z = fmaf(wv, v.z, acc.z);
        acc.w = fmaf(wv, v.w, acc.w);
    }
    out4[(size_t)b * 16384 + i4] = acc;
}

extern "C" void kernel_launch(void* const* d_in, const int* in_sizes, int n_in,
                              void* d_out, int out_size, void* d_ws, size_t ws_size,
                              hipStream_t stream) {
    const float* hid = (const float*)d_in[0];
    const float* enc = (const float*)d_in[1];
    const float* W1  = (const float*)d_in[2];
    const float* b1  = (const float*)d_in[3];
    const float* W2  = (const float*)d_in[4];
    const float* b2  = (const float*)d_in[5];
    float* out = (float*)d_out;

    float* ehb1    = out;                       // d_out reused as 4MB scratch
    float* partial = (float*)d_ws;              // 2048 floats
    unsigned char* packA = (unsigned char*)(partial + 2048);  // 128KB bf16 W1e

    prep_kernel<<<1056, 256, 0, stream>>>(hid, W1, b1, ehb1, (uint4v*)packA);
    energy_mfma<<<2048, 256, 0, stream>>>(enc, packA, W2, ehb1, partial);
    context_kernel<<<1024, 256, 0, stream>>>((const float4*)enc, partial, b2, (float4*)out);
}